// Round 2
// baseline (851.909 us; speedup 1.0000x reference)
//
#include <hip/hip_runtime.h>

#define B_   2
#define S_   1024
#define D_   4096
#define HQ_  32
#define HKV_ 8
#define HD_  128
#define SCALE_ 0.08838834764831845f

typedef unsigned short u16;
typedef __attribute__((ext_vector_type(8))) short s16x8;
typedef __attribute__((ext_vector_type(4))) short s16x4;
typedef __attribute__((ext_vector_type(4))) float f32x4;

#define MFMA(a,b,c) __builtin_amdgcn_mfma_f32_16x16x32_bf16((a),(b),(c),0,0,0)

__device__ __forceinline__ u16 bf16_rne(float x) {
  unsigned u = __float_as_uint(x);
  u += 0x7fffu + ((u >> 16) & 1u);
  return (u16)(u >> 16);
}
__device__ __forceinline__ float bf16_up(u16 h) {
  return __uint_as_float(((unsigned)h) << 16);
}
__device__ __forceinline__ void split2(float x, u16& h, u16& l) {
  h = bf16_rne(x);
  l = bf16_rne(x - bf16_up(h));
}

// ---- async global->LDS, 16B per lane ----
typedef const __attribute__((address_space(1))) void* gas_ptr;
typedef __attribute__((address_space(3))) void* las_ptr;
__device__ __forceinline__ void gload_lds16(const void* g, void* l) {
  __builtin_amdgcn_global_load_lds((gas_ptr)g, (las_ptr)l, 16, 0, 0);
}

// ===========================================================================
// Fragmentize A (M x K fp32, row-major) -> hi/lo bf16 fragment-ordered planes.
// Element (m,k) -> dh[(kt*(M/16)+mt)*512 + l*8 + j],
//   kt=k>>5, mt=m>>4, l=((k&31)>>3)*16 + (m&15), j=k&7.
// ===========================================================================
__global__ __launch_bounds__(256) void frag_a_kernel(
    const float* __restrict__ src, u16* __restrict__ dh, u16* __restrict__ dl,
    int M, int K)
{
  __shared__ float T[128][36];
  const int mb = blockIdx.x, kt = blockIdx.y;
  const int tid = threadIdx.x;
  const int row0 = tid >> 3, c4 = (tid & 7) * 4;
#pragma unroll
  for (int rep = 0; rep < 4; ++rep) {
    int row = row0 + rep * 32;
    float4 v = *reinterpret_cast<const float4*>(&src[(size_t)(mb*128 + row) * K + kt*32 + c4]);
    *reinterpret_cast<float4*>(&T[row][c4]) = v;
  }
  __syncthreads();
  const size_t base = ((size_t)kt * (M/16) + (size_t)mb * 8) * 512;
#pragma unroll
  for (int rep = 0; rep < 2; ++rep) {
    int c = tid + rep * 256;               // 0..511
    int mt = c >> 6, l = c & 63, kc = l >> 4, r = l & 15;
    u16 hh[8], ll[8];
#pragma unroll
    for (int j = 0; j < 8; ++j) split2(T[mt*16 + r][kc*8 + j], hh[j], ll[j]);
    *reinterpret_cast<s16x8*>(&dh[base + (size_t)c * 8]) =
      (s16x8){(short)hh[0],(short)hh[1],(short)hh[2],(short)hh[3],
              (short)hh[4],(short)hh[5],(short)hh[6],(short)hh[7]};
    *reinterpret_cast<s16x8*>(&dl[base + (size_t)c * 8]) =
      (s16x8){(short)ll[0],(short)ll[1],(short)ll[2],(short)ll[3],
              (short)ll[4],(short)ll[5],(short)ll[6],(short)ll[7]};
  }
}

// ===========================================================================
// Fragmentize B (K x N fp32 weights) -> transposed fragment-ordered planes.
// Element (k,n) -> dh[(kt*(N/16)+nt)*512 + l*8 + j],
//   kt=k>>5, nt=n>>4, l=((k&31)>>3)*16 + (n&15), j=k&7.
// ===========================================================================
__global__ __launch_bounds__(256) void frag_b_kernel(
    const float* __restrict__ W, u16* __restrict__ dh, u16* __restrict__ dl,
    int K, int N)
{
  __shared__ float T[32][68];
  const int kt = blockIdx.x, nb = blockIdx.y;
  const int tid = threadIdx.x;
#pragma unroll
  for (int rep = 0; rep < 2; ++rep) {
    int idx = tid + rep * 256;             // 0..511
    int row = idx >> 4, c4 = (idx & 15) * 4;
    float4 v = *reinterpret_cast<const float4*>(&W[(size_t)(kt*32 + row) * N + nb*64 + c4]);
    *reinterpret_cast<float4*>(&T[row][c4]) = v;
  }
  __syncthreads();
  const size_t base = ((size_t)kt * (N/16) + (size_t)nb * 4) * 512;
  int c = tid;                             // 0..255
  int nt = c >> 6, l = c & 63, kc = l >> 4, r = l & 15;
  u16 hh[8], ll[8];
#pragma unroll
  for (int j = 0; j < 8; ++j) split2(T[kc*8 + j][nt*16 + r], hh[j], ll[j]);
  *reinterpret_cast<s16x8*>(&dh[base + (size_t)c * 8]) =
    (s16x8){(short)hh[0],(short)hh[1],(short)hh[2],(short)hh[3],
            (short)hh[4],(short)hh[5],(short)hh[6],(short)hh[7]};
  *reinterpret_cast<s16x8*>(&dl[base + (size_t)c * 8]) =
    (s16x8){(short)ll[0],(short)ll[1],(short)ll[2],(short)ll[3],
            (short)ll[4],(short)ll[5],(short)ll[6],(short)ll[7]};
}

// ===========================================================================
// Fragment GEMM core: C[mb*128..+128, nb*256..+256] += A@B (3-pass hi/lo).
// LDS: Ah dbuf(2x8KB) + Bh dbuf(2x16KB) + Al(8KB) + Bl(16KB) = 72KB.
// Per physical K-tile: 3 vsteps, each {prefetch next plane, ds_read, 16 MFMA,
// syncthreads}. global_load_lds linear staging, conflict-free ds_read_b128.
// ===========================================================================
__device__ __forceinline__ void gemm_frag_core(
    const u16* __restrict__ FAh, const u16* __restrict__ FAl,
    const u16* __restrict__ FBh, const u16* __restrict__ FBl,
    float* __restrict__ C, int ldc, int MT16, int NT16,
    int mb, int nb, u16* lds)
{
  u16* ah0 = lds;             // 4096 u16
  u16* ah1 = lds + 4096;
  u16* bh0 = lds + 8192;      // 8192 u16
  u16* bh1 = lds + 16384;
  u16* Al  = lds + 24576;     // 4096
  u16* Bl  = lds + 28672;     // 8192

  const int tid  = threadIdx.x;
  const int lane = tid & 63;
  const int wid  = tid >> 6;
  const int mtb  = (wid >> 2) * 4;
  const int ntb  = (wid & 3) * 4;
  const int loff = lane * 8;

  f32x4 acc[4][4];
#pragma unroll
  for (int i = 0; i < 4; ++i)
#pragma unroll
    for (int j = 0; j < 4; ++j) acc[i][j] = (f32x4){0.f, 0.f, 0.f, 0.f};

  const size_t aStep = (size_t)MT16 * 512;
  const size_t bStep = (size_t)NT16 * 512;
  const u16* pAh = FAh + (size_t)mb * 8 * 512;
  const u16* pAl = FAl + (size_t)mb * 8 * 512;
  const u16* pBh = FBh + (size_t)nb * 16 * 512;
  const u16* pBl = FBl + (size_t)nb * 16 * 512;

  // prologue: stage Ah[0], Bh[0]
  gload_lds16(pAh + wid*512 + loff, ah0 + wid*512);
  gload_lds16(pBh + wid*512 + loff, bh0 + wid*512);
  gload_lds16(pBh + (wid+8)*512 + loff, bh0 + (wid+8)*512);
  __syncthreads();

  for (int kt = 0; kt < 128; ++kt) {
    u16* cAh = (kt & 1) ? ah1 : ah0;
    u16* cBh = (kt & 1) ? bh1 : bh0;
    u16* nAh = (kt & 1) ? ah0 : ah1;
    u16* nBh = (kt & 1) ? bh0 : bh1;

    s16x8 a_h[4], b_h[4], a_l[4], b_l[4];

    // ---- vstep 0: Ah x Bh ; prefetch Al[kt] ----
    {
      const u16* g = pAl + (size_t)kt * aStep;
      gload_lds16(g + wid*512 + loff, Al + wid*512);
    }
#pragma unroll
    for (int mf = 0; mf < 4; ++mf)
      a_h[mf] = *reinterpret_cast<const s16x8*>(&cAh[(mtb+mf)*512 + loff]);
#pragma unroll
    for (int nf = 0; nf < 4; ++nf)
      b_h[nf] = *reinterpret_cast<const s16x8*>(&cBh[(ntb+nf)*512 + loff]);
#pragma unroll
    for (int mf = 0; mf < 4; ++mf)
#pragma unroll
      for (int nf = 0; nf < 4; ++nf)
        acc[mf][nf] = MFMA(a_h[mf], b_h[nf], acc[mf][nf]);
    __syncthreads();

    // ---- vstep 1: Al x Bh ; prefetch Bl[kt] ----
    {
      const u16* g = pBl + (size_t)kt * bStep;
      gload_lds16(g + wid*512 + loff, Bl + wid*512);
      gload_lds16(g + (wid+8)*512 + loff, Bl + (wid+8)*512);
    }
#pragma unroll
    for (int mf = 0; mf < 4; ++mf)
      a_l[mf] = *reinterpret_cast<const s16x8*>(&Al[(mtb+mf)*512 + loff]);
#pragma unroll
    for (int mf = 0; mf < 4; ++mf)
#pragma unroll
      for (int nf = 0; nf < 4; ++nf)
        acc[mf][nf] = MFMA(a_l[mf], b_h[nf], acc[mf][nf]);
    __syncthreads();

    // ---- vstep 2: Ah x Bl ; prefetch Ah[kt+1], Bh[kt+1] ----
    if (kt < 127) {
      const u16* ga = pAh + (size_t)(kt+1) * aStep;
      const u16* gb = pBh + (size_t)(kt+1) * bStep;
      gload_lds16(ga + wid*512 + loff, nAh + wid*512);
      gload_lds16(gb + wid*512 + loff, nBh + wid*512);
      gload_lds16(gb + (wid+8)*512 + loff, nBh + (wid+8)*512);
    }
#pragma unroll
    for (int nf = 0; nf < 4; ++nf)
      b_l[nf] = *reinterpret_cast<const s16x8*>(&Bl[(ntb+nf)*512 + loff]);
#pragma unroll
    for (int mf = 0; mf < 4; ++mf)
#pragma unroll
      for (int nf = 0; nf < 4; ++nf)
        acc[mf][nf] = MFMA(a_h[mf], b_l[nf], acc[mf][nf]);
    __syncthreads();
  }

  // ---- epilogue ----
  const int lr = lane & 15, lg = lane >> 4;
  const int row0 = mb*128 + (wid >> 2) * 64;
  const int col0 = nb*256 + (wid & 3) * 64;
#pragma unroll
  for (int mf = 0; mf < 4; ++mf)
#pragma unroll
    for (int nf = 0; nf < 4; ++nf)
#pragma unroll
      for (int r = 0; r < 4; ++r)
        C[(size_t)(row0 + mf*16 + lg*4 + r) * ldc + col0 + nf*16 + lr] = acc[mf][nf][r];
}

__global__ __launch_bounds__(512) void gemm_qkv_frag(
    const u16* __restrict__ FXh, const u16* __restrict__ FXl,
    const u16* __restrict__ FQh, const u16* __restrict__ FQl,
    const u16* __restrict__ FKh, const u16* __restrict__ FKl,
    const u16* __restrict__ FVh, const u16* __restrict__ FVl,
    float* __restrict__ qb, float* __restrict__ kb, float* __restrict__ vb)
{
  __shared__ __attribute__((aligned(16))) u16 lds[36864];
  int id = blockIdx.x;                       // 0..383
  int swz = (id & 7) * 48 + (id >> 3);       // bijective XCD swizzle
  int mb = swz / 24, t = swz % 24;
  const u16 *Bh_, *Bl_; float* C; int NT16, nb, ldc;
  if (t < 16)      { Bh_ = FQh; Bl_ = FQl; C = qb; NT16 = 256; nb = t;      ldc = 4096; }
  else if (t < 20) { Bh_ = FKh; Bl_ = FKl; C = kb; NT16 = 64;  nb = t - 16; ldc = 1024; }
  else             { Bh_ = FVh; Bl_ = FVl; C = vb; NT16 = 64;  nb = t - 20; ldc = 1024; }
  gemm_frag_core(FXh, FXl, Bh_, Bl_, C, ldc, 128, NT16, mb, nb, lds);
}

__global__ __launch_bounds__(512) void gemm_out_frag(
    const u16* __restrict__ FAh, const u16* __restrict__ FAl,
    const u16* __restrict__ FOh, const u16* __restrict__ FOl,
    float* __restrict__ out)
{
  __shared__ __attribute__((aligned(16))) u16 lds[36864];
  int id = blockIdx.x;                       // 0..255
  int swz = (id & 7) * 32 + (id >> 3);
  int mb = swz >> 4, nb = swz & 15;
  gemm_frag_core(FAh, FAl, FOh, FOl, out, 4096, 128, 256, mb, nb, lds);
}

// ===========================================================================
// Fallback GEMM (round-1, in-loop split) used only if ws is too small.
// ===========================================================================
__device__ __forceinline__ void gemm_core_128x256(
    const float* __restrict__ A, const float* __restrict__ W,
    float* __restrict__ C, int ldw, int m0, int n0)
{
  __shared__ u16 Ah[128][40];
  __shared__ u16 Al[128][40];
  __shared__ u16 Bh[256][40];
  __shared__ u16 Bl[256][40];

  const int tid  = threadIdx.x;
  const int lane = tid & 63;
  const int wid  = tid >> 6;
  const int wm   = (wid >> 2) * 64;
  const int wn   = (wid & 3) * 64;
  const int lr   = lane & 15;
  const int lg   = lane >> 4;

  f32x4 acc[4][4];
#pragma unroll
  for (int i = 0; i < 4; ++i)
#pragma unroll
    for (int j = 0; j < 4; ++j) acc[i][j] = (f32x4){0.f, 0.f, 0.f, 0.f};

  const int ar  = tid >> 3;
  const int ak  = (tid & 7) * 4;
  const int bn  = tid & 255;
  const int bk0 = (tid >> 8) * 16;

  for (int kt = 0; kt < D_ / 32; ++kt) {
    const int k0 = kt * 32;
    __syncthreads();
#pragma unroll
    for (int j = 0; j < 2; ++j) {
      int r = ar + 64 * j;
      float4 v = *reinterpret_cast<const float4*>(&A[(size_t)(m0 + r) * D_ + k0 + ak]);
      u16 h0,h1,h2,h3,l0,l1,l2,l3;
      split2(v.x,h0,l0); split2(v.y,h1,l1); split2(v.z,h2,l2); split2(v.w,h3,l3);
      *reinterpret_cast<s16x4*>(&Ah[r][ak]) = (s16x4){(short)h0,(short)h1,(short)h2,(short)h3};
      *reinterpret_cast<s16x4*>(&Al[r][ak]) = (s16x4){(short)l0,(short)l1,(short)l2,(short)l3};
    }
    {
      const float* wp = W + (size_t)(k0 + bk0) * ldw + (n0 + bn);
#pragma unroll
      for (int q = 0; q < 4; ++q) {
        float v0 = wp[(q*4 + 0) * (size_t)ldw];
        float v1 = wp[(q*4 + 1) * (size_t)ldw];
        float v2 = wp[(q*4 + 2) * (size_t)ldw];
        float v3 = wp[(q*4 + 3) * (size_t)ldw];
        u16 h0,h1,h2,h3,l0,l1,l2,l3;
        split2(v0,h0,l0); split2(v1,h1,l1); split2(v2,h2,l2); split2(v3,h3,l3);
        *reinterpret_cast<s16x4*>(&Bh[bn][bk0 + q*4]) = (s16x4){(short)h0,(short)h1,(short)h2,(short)h3};
        *reinterpret_cast<s16x4*>(&Bl[bn][bk0 + q*4]) = (s16x4){(short)l0,(short)l1,(short)l2,(short)l3};
      }
    }
    __syncthreads();
    s16x8 a_h[4], a_l[4], b_h[4], b_l[4];
#pragma unroll
    for (int mf = 0; mf < 4; ++mf) {
      a_h[mf] = *reinterpret_cast<const s16x8*>(&Ah[wm + mf*16 + lr][lg*8]);
      a_l[mf] = *reinterpret_cast<const s16x8*>(&Al[wm + mf*16 + lr][lg*8]);
    }
#pragma unroll
    for (int nf = 0; nf < 4; ++nf) {
      b_h[nf] = *reinterpret_cast<const s16x8*>(&Bh[wn + nf*16 + lr][lg*8]);
      b_l[nf] = *reinterpret_cast<const s16x8*>(&Bl[wn + nf*16 + lr][lg*8]);
    }
#pragma unroll
    for (int mf = 0; mf < 4; ++mf)
#pragma unroll
      for (int nf = 0; nf < 4; ++nf) {
        acc[mf][nf] = MFMA(a_h[mf], b_h[nf], acc[mf][nf]);
        acc[mf][nf] = MFMA(a_l[mf], b_h[nf], acc[mf][nf]);
        acc[mf][nf] = MFMA(a_h[mf], b_l[nf], acc[mf][nf]);
      }
  }
#pragma unroll
  for (int mf = 0; mf < 4; ++mf)
#pragma unroll
    for (int nf = 0; nf < 4; ++nf)
#pragma unroll
      for (int r = 0; r < 4; ++r) {
        int row = m0 + wm + mf*16 + lg*4 + r;
        int col = n0 + wn + nf*16 + lr;
        C[(size_t)row * ldw + col] = acc[mf][nf][r];
      }
}

__global__ __launch_bounds__(512) void gemm_qkv_kernel(
    const float* __restrict__ X,
    const float* __restrict__ Wq, const float* __restrict__ Wk,
    const float* __restrict__ Wv,
    float* __restrict__ qb, float* __restrict__ kb, float* __restrict__ vb)
{
  int nb = blockIdx.x;
  int m0 = blockIdx.y * 128;
  const float* W; float* C; int ldw, n0;
  if (nb < 16)      { W = Wq; C = qb; ldw = HQ_*HD_;  n0 = nb * 256; }
  else if (nb < 20) { W = Wk; C = kb; ldw = HKV_*HD_; n0 = (nb-16) * 256; }
  else              { W = Wv; C = vb; ldw = HKV_*HD_; n0 = (nb-20) * 256; }
  gemm_core_128x256(X, W, C, ldw, m0, n0);
}

__global__ __launch_bounds__(512) void gemm_out_kernel(
    const float* __restrict__ A, const float* __restrict__ Wo, float* __restrict__ out)
{
  gemm_core_128x256(A, Wo, out, D_, blockIdx.y * 128, blockIdx.x * 256);
}

// ---------------------------------------------------------------------------
// RoPE in-place on q (b,s,32,128) and k (b,s,8,128), fp32.
// ---------------------------------------------------------------------------
__global__ __launch_bounds__(256) void rope_kernel(
    float* __restrict__ qb, float* __restrict__ kb,
    const float* __restrict__ cosT, const float* __restrict__ sinT)
{
  int idx = blockIdx.x * 256 + threadIdx.x;
  const int nq = B_ * S_ * HQ_ * (HD_/2);
  const int nk = B_ * S_ * HKV_ * (HD_/2);
  if (idx < nq) {
    int j = idx & 63;
    int h = (idx >> 6) & (HQ_ - 1);
    int bs = idx >> 11;
    float* p = qb + ((size_t)bs * HQ_ + h) * HD_;
    const float* cp = cosT + (size_t)bs * HD_;
    const float* sp = sinT + (size_t)bs * HD_;
    float x1 = p[j], x2 = p[j + 64];
    p[j]      = x1 * cp[j]      - x2 * sp[j];
    p[j + 64] = x2 * cp[j + 64] + x1 * sp[j + 64];
  } else if (idx < nq + nk) {
    int t2 = idx - nq;
    int j = t2 & 63;
    int h = (t2 >> 6) & (HKV_ - 1);
    int bs = t2 >> 9;
    float* p = kb + ((size_t)bs * HKV_ + h) * HD_;
    const float* cp = cosT + (size_t)bs * HD_;
    const float* sp = sinT + (size_t)bs * HD_;
    float x1 = p[j], x2 = p[j + 64];
    p[j]      = x1 * cp[j]      - x2 * sp[j];
    p[j + 64] = x2 * cp[j + 64] + x1 * sp[j + 64];
  }
}

// ---------------------------------------------------------------------------
// Flash attention (round-1 verified): grid (8 qtiles, 64 b*h), 512 thr.
// ---------------------------------------------------------------------------
__global__ __launch_bounds__(512) void attn_kernel(
    const float* __restrict__ qb, const float* __restrict__ kb,
    const float* __restrict__ vb, float* __restrict__ ob)
{
  __shared__ u16 Kh[64][136], Kl[64][136];
  __shared__ u16 Vh[128][72], Vl[128][72];
  __shared__ u16 Ph[8][16][72], Pl[8][16][72];

  const int tid  = threadIdx.x;
  const int lane = tid & 63;
  const int wid  = tid >> 6;
  const int lr   = lane & 15;
  const int lg   = lane >> 4;
  const int qt   = blockIdx.x;
  const int bh   = blockIdx.y;
  const int b    = bh >> 5, h = bh & 31, kvh = h >> 2;

  s16x8 qh[4], ql[4];
  {
    const int qrow = qt * 128 + wid * 16 + lr;
    const float* qp = qb + ((size_t)((b * S_ + qrow) * HQ_ + h)) * HD_;
#pragma unroll
    for (int kc = 0; kc < 4; ++kc) {
      const float* qp2 = qp + kc * 32 + lg * 8;
      float4 v0 = *reinterpret_cast<const float4*>(qp2);
      float4 v1 = *reinterpret_cast<const float4*>(qp2 + 4);
      u16 hh[8], ll[8];
      split2(v0.x,hh[0],ll[0]); split2(v0.y,hh[1],ll[1]);
      split2(v0.z,hh[2],ll[2]); split2(v0.w,hh[3],ll[3]);
      split2(v1.x,hh[4],ll[4]); split2(v1.y,hh[5],ll[5]);
      split2(v1.z,hh[6],ll[6]); split2(v1.w,hh[7],ll[7]);
      qh[kc] = (s16x8){(short)hh[0],(short)hh[1],(short)hh[2],(short)hh[3],
                       (short)hh[4],(short)hh[5],(short)hh[6],(short)hh[7]};
      ql[kc] = (s16x8){(short)ll[0],(short)ll[1],(short)ll[2],(short)ll[3],
                       (short)ll[4],(short)ll[5],(short)ll[6],(short)ll[7]};
    }
  }

  f32x4 acc_o[8];
#pragma unroll
  for (int df = 0; df < 8; ++df) acc_o[df] = (f32x4){0.f, 0.f, 0.f, 0.f};
  float m_run[4] = {-1e30f, -1e30f, -1e30f, -1e30f};
  float l_run[4] = {0.f, 0.f, 0.f, 0.f};

  const float* kbase = kb + ((size_t)(b * S_) * HKV_ + kvh) * HD_;
  const float* vbase = vb + ((size_t)(b * S_) * HKV_ + kvh) * HD_;

  for (int t = 0; t < S_ / 64; ++t) {
    const int kk0 = t * 64;
    __syncthreads();
#pragma unroll
    for (int j = 0; j < 4; ++j) {
      int idx = tid + 512 * j;
      int kk = idx >> 5, dq = (idx & 31) * 4;
      float4 v = *reinterpret_cast<const float4*>(kbase + (size_t)(kk0 + kk) * (HKV_*HD_) + dq);
      u16 h0,h1,h2,h3,l0,l1,l2,l3;
      split2(v.x,h0,l0); split2(v.y,h1,l1); split2(v.z,h2,l2); split2(v.w,h3,l3);
      *reinterpret_cast<s16x4*>(&Kh[kk][dq]) = (s16x4){(short)h0,(short)h1,(short)h2,(short)h3};
      *reinterpret_cast<s16x4*>(&Kl[kk][dq]) = (s16x4){(short)l0,(short)l1,(short)l2,(short)l3};
    }
    {
      int d = tid & 127;
      int kkb = (tid >> 7) * 16;
      const float* vcol = vbase + d;
#pragma unroll
      for (int jq = 0; jq < 4; ++jq) {
        u16 h4[4], l4[4];
#pragma unroll
        for (int e = 0; e < 4; ++e) {
          float val = vcol[(size_t)(kk0 + kkb + jq*4 + e) * (HKV_*HD_)];
          split2(val, h4[e], l4[e]);
        }
        *reinterpret_cast<s16x4*>(&Vh[d][kkb + jq*4]) = (s16x4){(short)h4[0],(short)h4[1],(short)h4[2],(short)h4[3]};
        *reinterpret_cast<s16x4*>(&Vl[d][kkb + jq*4]) = (s16x4){(short)l4[0],(short)l4[1],(short)l4[2],(short)l4[3]};
      }
    }
    __syncthreads();
    f32x4 accs[4];
#pragma unroll
    for (int nf = 0; nf < 4; ++nf) accs[nf] = (f32x4){0.f, 0.f, 0.f, 0.f};
#pragma unroll
    for (int nf = 0; nf < 4; ++nf) {
      int krow = nf * 16 + lr;
#pragma unroll
      for (int kc = 0; kc < 4; ++kc) {
        s16x8 kh8 = *reinterpret_cast<const s16x8*>(&Kh[krow][kc*32 + lg*8]);
        s16x8 kl8 = *reinterpret_cast<const s16x8*>(&Kl[krow][kc*32 + lg*8]);
        accs[nf] = MFMA(qh[kc], kh8, accs[nf]);
        accs[nf] = MFMA(ql[kc], kh8, accs[nf]);
        accs[nf] = MFMA(qh[kc], kl8, accs[nf]);
      }
    }
#pragma unroll
    for (int nf = 0; nf < 4; ++nf) accs[nf] *= SCALE_;
    float corr[4], rsum[4];
#pragma unroll
    for (int r = 0; r < 4; ++r) {
      float t0 = fmaxf(fmaxf(accs[0][r], accs[1][r]), fmaxf(accs[2][r], accs[3][r]));
      t0 = fmaxf(t0, __shfl_xor(t0, 1));
      t0 = fmaxf(t0, __shfl_xor(t0, 2));
      t0 = fmaxf(t0, __shfl_xor(t0, 4));
      t0 = fmaxf(t0, __shfl_xor(t0, 8));
      float mnew = fmaxf(m_run[r], t0);
      corr[r] = __expf(m_run[r] - mnew);
      m_run[r] = mnew;
      rsum[r] = 0.f;
    }
#pragma unroll
    for (int nf = 0; nf < 4; ++nf)
#pragma unroll
      for (int r = 0; r < 4; ++r) {
        float p = __expf(accs[nf][r] - m_run[r]);
        rsum[r] += p;
        u16 ph, pl;
        split2(p, ph, pl);
        Ph[wid][lg*4 + r][nf*16 + lr] = ph;
        Pl[wid][lg*4 + r][nf*16 + lr] = pl;
      }
#pragma unroll
    for (int r = 0; r < 4; ++r) {
      float s = rsum[r];
      s += __shfl_xor(s, 1); s += __shfl_xor(s, 2);
      s += __shfl_xor(s, 4); s += __shfl_xor(s, 8);
      l_run[r] = l_run[r] * corr[r] + s;
    }
#pragma unroll
    for (int df = 0; df < 8; ++df)
#pragma unroll
      for (int r = 0; r < 4; ++r) acc_o[df][r] *= corr[r];
    s16x8 pa_h[2], pa_l[2];
#pragma unroll
    for (int kc = 0; kc < 2; ++kc) {
      pa_h[kc] = *reinterpret_cast<const s16x8*>(&Ph[wid][lr][kc*32 + lg*8]);
      pa_l[kc] = *reinterpret_cast<const s16x8*>(&Pl[wid][lr][kc*32 + lg*8]);
    }
#pragma unroll
    for (int df = 0; df < 8; ++df) {
      int dcol = df * 16 + lr;
#pragma unroll
      for (int kc = 0; kc < 2; ++kc) {
        s16x8 vh8 = *reinterpret_cast<const s16x8*>(&Vh[dcol][kc*32 + lg*8]);
        s16x8 vl8 = *reinterpret_cast<const s16x8*>(&Vl[dcol][kc*32 + lg*8]);
        acc_o[df] = MFMA(pa_h[kc], vh8, acc_o[df]);
        acc_o[df] = MFMA(pa_l[kc], vh8, acc_o[df]);
        acc_o[df] = MFMA(pa_h[kc], vl8, acc_o[df]);
      }
    }
  }
  float inv_l[4];
#pragma unroll
  for (int r = 0; r < 4; ++r) inv_l[r] = 1.f / l_run[r];
#pragma unroll
  for (int df = 0; df < 8; ++df)
#pragma unroll
    for (int r = 0; r < 4; ++r) {
      int row = qt * 128 + wid * 16 + lg * 4 + r;
      ob[((size_t)((b * S_ + row) * HQ_ + h)) * HD_ + df*16 + lr] = acc_o[df][r] * inv_l[r];
    }
}

// ---------------------------------------------------------------------------
extern "C" void kernel_launch(void* const* d_in, const int* in_sizes, int n_in,
                              void* d_out, int out_size, void* d_ws, size_t ws_size,
                              hipStream_t stream)
{
  const float* hs   = (const float*)d_in[0];
  const float* cosT = (const float*)d_in[1];
  const float* sinT = (const float*)d_in[2];
  const float* Wq   = (const float*)d_in[3];
  const float* Wk   = (const float*)d_in[4];
  const float* Wv   = (const float*)d_in[5];
  const float* Wo   = (const float*)d_in[6];
  float* out = (float*)d_out;

  float* qb = (float*)d_ws;                 // 8388608 f32
  float* kb = qb + 8388608;                 // 2097152
  float* vb = kb + 2097152;                 // 2097152
  float* ab = vb + 2097152;                 // 8388608

  const size_t REQ = 285212672ULL;          // 272 MB
  int total = B_*S_*HQ_*(HD_/2) + B_*S_*HKV_*(HD_/2);

  if (ws_size >= REQ) {
    u16* base = (u16*)(ab + 8388608);
    u16* FXh = base;                        // 8388608 u16 (also reused as FA)
    u16* FXl = FXh + 8388608;
    u16* FQh = FXl + 8388608;               // 16777216
    u16* FQl = FQh + 16777216;
    u16* FKh = FQl + 16777216;              // 4194304
    u16* FKl = FKh + 4194304;
    u16* FVh = FKl + 4194304;               // 4194304
    u16* FVl = FVh + 4194304;
    u16* FOh = FVl + 4194304;               // 16777216
    u16* FOl = FOh + 16777216;

    frag_a_kernel<<<dim3(16,128), 256, 0, stream>>>(hs, FXh, FXl, 2048, 4096);
    frag_b_kernel<<<dim3(128,64), 256, 0, stream>>>(Wq, FQh, FQl, 4096, 4096);
    frag_b_kernel<<<dim3(128,16), 256, 0, stream>>>(Wk, FKh, FKl, 4096, 1024);
    frag_b_kernel<<<dim3(128,16), 256, 0, stream>>>(Wv, FVh, FVl, 4096, 1024);
    frag_b_kernel<<<dim3(128,64), 256, 0, stream>>>(Wo, FOh, FOl, 4096, 4096);

    gemm_qkv_frag<<<384, 512, 0, stream>>>(FXh, FXl, FQh, FQl, FKh, FKl, FVh, FVl,
                                           qb, kb, vb);
    rope_kernel<<<dim3((total + 255)/256), 256, 0, stream>>>(qb, kb, cosT, sinT);
    attn_kernel<<<dim3(8, 64), 512, 0, stream>>>(qb, kb, vb, ab);

    frag_a_kernel<<<dim3(16,128), 256, 0, stream>>>(ab, FXh, FXl, 2048, 4096);
    gemm_out_frag<<<256, 512, 0, stream>>>(FXh, FXl, FOh, FOl, out);
  } else {
    // fallback: round-1 path (84 MB ws)
    gemm_qkv_kernel<<<dim3(24, 16), 512, 0, stream>>>(hs, Wq, Wk, Wv, qb, kb, vb);
    rope_kernel<<<dim3((total + 255)/256), 256, 0, stream>>>(qb, kb, cosT, sinT);
    attn_kernel<<<dim3(8, 64), 512, 0, stream>>>(qb, kb, vb, ab);
    gemm_out_kernel<<<dim3(16, 16), 512, 0, stream>>>(ab, Wo, out);
  }
}

// Round 4
// 763.269 us; speedup vs baseline: 1.1161x; 1.1161x over previous
//
#include <hip/hip_runtime.h>

#define B_   2
#define S_   1024
#define D_   4096
#define HQ_  32
#define HKV_ 8
#define HD_  128
#define SCALE_ 0.08838834764831845f

typedef unsigned short u16;
typedef __attribute__((ext_vector_type(8))) short s16x8;
typedef __attribute__((ext_vector_type(4))) short s16x4;
typedef __attribute__((ext_vector_type(4))) float f32x4;

#define MFMA(a,b,c) __builtin_amdgcn_mfma_f32_16x16x32_bf16((a),(b),(c),0,0,0)

__device__ __forceinline__ u16 bf16_rne(float x) {
  unsigned u = __float_as_uint(x);
  u += 0x7fffu + ((u >> 16) & 1u);
  return (u16)(u >> 16);
}
__device__ __forceinline__ float bf16_up(u16 h) {
  return __uint_as_float(((unsigned)h) << 16);
}
__device__ __forceinline__ void split2(float x, u16& h, u16& l) {
  h = bf16_rne(x);
  l = bf16_rne(x - bf16_up(h));
}

// packed hi/lo split: 2 elems -> 1 u32 hi + 1 u32 lo
__device__ __forceinline__ void cvt_hi_lo(float a, float b, unsigned& hi, unsigned& lo) {
  unsigned h, l;
  asm("v_cvt_pk_bf16_f32 %0, %1, %2" : "=v"(h) : "v"(a), "v"(b));
  float ra = __uint_as_float(h << 16);
  float rb = __uint_as_float(h & 0xffff0000u);
  float la = a - ra, lb = b - rb;
  asm("v_cvt_pk_bf16_f32 %0, %1, %2" : "=v"(l) : "v"(la), "v"(lb));
  hi = h; lo = l;
}
__device__ __forceinline__ void pack8(float4 x, float4 y, uint4& h, uint4& l) {
  unsigned h0,h1,h2,h3,l0,l1,l2,l3;
  cvt_hi_lo(x.x, x.y, h0, l0);
  cvt_hi_lo(x.z, x.w, h1, l1);
  cvt_hi_lo(y.x, y.y, h2, l2);
  cvt_hi_lo(y.z, y.w, h3, l3);
  h = make_uint4(h0,h1,h2,h3); l = make_uint4(l0,l1,l2,l3);
}

// ---- async global->LDS, 16B per lane (dest = wave-uniform base) ----
typedef const __attribute__((address_space(1))) void* gas_ptr;
typedef __attribute__((address_space(3))) void* las_ptr;
__device__ __forceinline__ void gload_lds16(const void* g, void* l) {
  __builtin_amdgcn_global_load_lds((gas_ptr)g, (las_ptr)l, 16, 0, 0);
}

// ===========================================================================
// frag_b: weights (K x N fp32) -> transposed fragment-ordered hi/lo planes,
// over a column chunk [n0, n0 + Nc16*16). Element (k, n0+nc):
//   dh[(kt*Nc16 + nc>>4)*512 + l*8 + j], l=((k&31)>>3)*16 + (nc&15), j=k&7.
// grid: (K/32, Nc/64), 256 threads. Plane size = 128 * Nc16 * 512 u16.
// ===========================================================================
__global__ __launch_bounds__(256) void frag_b(
    const float* __restrict__ W, u16* __restrict__ dh, u16* __restrict__ dl,
    int N, int n0, int Nc16)
{
  __shared__ float T[32][68];
  const int kt = blockIdx.x, nbk = blockIdx.y;
  const int tid = threadIdx.x;
#pragma unroll
  for (int rep = 0; rep < 2; ++rep) {
    int idx = tid + rep * 256;
    int row = idx >> 4, c4 = (idx & 15) * 4;
    float4 v = *reinterpret_cast<const float4*>(&W[(size_t)(kt*32 + row) * N + n0 + nbk*64 + c4]);
    *reinterpret_cast<float4*>(&T[row][c4]) = v;
  }
  __syncthreads();
  const size_t base = ((size_t)kt * Nc16 + nbk * 4) * 512;
  int c = tid;
  int nt = c >> 6, l = c & 63, kc = l >> 4, r = l & 15;
  u16 hh[8], ll[8];
#pragma unroll
  for (int j = 0; j < 8; ++j) split2(T[kc*8 + j][nt*16 + r], hh[j], ll[j]);
  *reinterpret_cast<s16x8*>(&dh[base + (size_t)c * 8]) =
    (s16x8){(short)hh[0],(short)hh[1],(short)hh[2],(short)hh[3],
            (short)hh[4],(short)hh[5],(short)hh[6],(short)hh[7]};
  *reinterpret_cast<s16x8*>(&dl[base + (size_t)c * 8]) =
    (s16x8){(short)ll[0],(short)ll[1],(short)ll[2],(short)ll[3],
            (short)ll[4],(short)ll[5],(short)ll[6],(short)ll[7]};
}

// ===========================================================================
// Hybrid GEMM: A fp32 (M x 4096) staged in-kernel (cvt_pk split, frag-order
// LDS writes, conflict-free); B pre-fragmented hi/lo planes (gload_lds).
// Tile 128x256, 512 thr = 8 waves (2m x 4n), 3-pass hi/lo MFMA.
// Plane sizes (u16): Wq/Wo-half = 8388608, Wk/Wv = 4194304, Wo-full = 16777216.
// modes: 0=QA+K+V(256 blk), 1=Q-half(128, qb+col0), 2=K+V(128),
//        3=OUT full(256), 4=OUT-half(128, out+col0)
// WF u16-offset layouts:
//  mode0/1: Wq-chunk hi@0 lo@8388608; Wk hi@16777216 lo@20971520;
//           Wv hi@25165824 lo@29360128
//  mode2:   Wk hi@0 lo@4194304; Wv hi@8388608 lo@12582912
//  mode3:   Wo hi@0 lo@16777216
//  mode4:   Wo-chunk hi@0 lo@8388608
// ===========================================================================
__global__ __launch_bounds__(512) void gemm_p1(
    const float* __restrict__ X, const float* __restrict__ abp,
    const u16* __restrict__ WF,
    float* __restrict__ qb, float* __restrict__ kb, float* __restrict__ vb,
    float* __restrict__ outp, int mode, int col0)
{
  __shared__ __attribute__((aligned(16))) u16 lds[40960];
  u16* ah0 = lds;
  u16* al0 = lds + 4096;
  u16* ah1 = lds + 8192;
  u16* al1 = lds + 12288;
  u16* bh0 = lds + 16384;
  u16* bh1 = lds + 24576;
  u16* blb = lds + 32768;

  const int id   = blockIdx.x;
  const int cpx  = gridDim.x >> 3;
  const int swz  = (id & 7) * cpx + (id >> 3);

  const float* A; const u16* Bh; const u16* Bl; float* C;
  int ldc, Nc16, mb, nb;
  if (mode == 0) {
    if (swz < 128)      { A=X; Bh=WF;          Bl=WF+8388608;  C=qb; ldc=4096; Nc16=128; mb=swz>>3; nb=swz&7; }
    else if (swz < 192) { int u=swz-128; A=X; Bh=WF+16777216; Bl=WF+20971520; C=kb; ldc=1024; Nc16=64; mb=u>>2; nb=u&3; }
    else                { int u=swz-192; A=X; Bh=WF+25165824; Bl=WF+29360128; C=vb; ldc=1024; Nc16=64; mb=u>>2; nb=u&3; }
  } else if (mode == 1) {
    A=X; Bh=WF; Bl=WF+8388608; C=qb+col0; ldc=4096; Nc16=128; mb=swz>>3; nb=swz&7;
  } else if (mode == 2) {
    if (swz < 64) { A=X; Bh=WF;          Bl=WF+4194304;  C=kb; ldc=1024; Nc16=64; mb=swz>>2; nb=swz&3; }
    else          { int u=swz-64; A=X; Bh=WF+8388608; Bl=WF+12582912; C=vb; ldc=1024; Nc16=64; mb=u>>2; nb=u&3; }
  } else if (mode == 3) {
    A=abp; Bh=WF; Bl=WF+16777216; C=outp; ldc=4096; Nc16=256; mb=swz>>4; nb=swz&15;
  } else {
    A=abp; Bh=WF; Bl=WF+8388608; C=outp+col0; ldc=4096; Nc16=128; mb=swz>>3; nb=swz&7;
  }

  const int tid  = threadIdx.x;
  const int lane = tid & 63;
  const int wid  = tid >> 6;
  const int mtb  = (wid >> 2) * 4;
  const int ntb  = (wid & 3) * 4;
  const int loff = lane * 8;

  // A staging geometry: thread owns row = tid>>2, k-chunk akc = tid&3 (8 k)
  const int arow = tid >> 2;
  const int akc  = tid & 3;
  const float* aptr = A + (size_t)(mb*128 + arow) * 4096 + akc*8;
  const int awr = (arow >> 4)*512 + (akc*16 + (arow & 15))*8;

  const size_t bStep = (size_t)Nc16 * 512;
  const u16* pBh = Bh + (size_t)nb*16*512 + loff;
  const u16* pBl = Bl + (size_t)nb*16*512 + loff;

  f32x4 acc[4][4];
#pragma unroll
  for (int i = 0; i < 4; ++i)
#pragma unroll
    for (int j = 0; j < 4; ++j) acc[i][j] = (f32x4){0.f, 0.f, 0.f, 0.f};

  // ---- prologue: A(kt=0) -> ah0/al0; B hi(kt=0) -> bh0; prefetch A(kt=1) ----
  float4 ra0 = *reinterpret_cast<const float4*>(aptr);
  float4 ra1 = *reinterpret_cast<const float4*>(aptr + 4);
  {
    uint4 h4, l4; pack8(ra0, ra1, h4, l4);
    *reinterpret_cast<uint4*>(&ah0[awr]) = h4;
    *reinterpret_cast<uint4*>(&al0[awr]) = l4;
  }
  gload_lds16(pBh + (size_t)wid*512,     bh0 + wid*512);
  gload_lds16(pBh + (size_t)(wid+8)*512, bh0 + (wid+8)*512);
  ra0 = *reinterpret_cast<const float4*>(aptr + 32);
  ra1 = *reinterpret_cast<const float4*>(aptr + 36);
  __syncthreads();

  for (int kt = 0; kt < 128; ++kt) {
    u16* cAh = (kt & 1) ? ah1 : ah0;
    u16* cAl = (kt & 1) ? al1 : al0;
    u16* nAh = (kt & 1) ? ah0 : ah1;
    u16* nAl = (kt & 1) ? al0 : al1;
    u16* cBh = (kt & 1) ? bh1 : bh0;
    u16* nBh = (kt & 1) ? bh0 : bh1;

    // ---- phase A: prefetch Bl[kt] + Bh[kt+1]; MFMA (ah+al) x bh ----
    gload_lds16(pBl + (size_t)kt*bStep + (size_t)wid*512,     blb + wid*512);
    gload_lds16(pBl + (size_t)kt*bStep + (size_t)(wid+8)*512, blb + (wid+8)*512);
    if (kt < 127) {
      gload_lds16(pBh + (size_t)(kt+1)*bStep + (size_t)wid*512,     nBh + wid*512);
      gload_lds16(pBh + (size_t)(kt+1)*bStep + (size_t)(wid+8)*512, nBh + (wid+8)*512);
    }
    s16x8 a_h[4], a_l[4], b_h[4];
#pragma unroll
    for (int mf = 0; mf < 4; ++mf) {
      a_h[mf] = *reinterpret_cast<const s16x8*>(&cAh[(mtb+mf)*512 + loff]);
      a_l[mf] = *reinterpret_cast<const s16x8*>(&cAl[(mtb+mf)*512 + loff]);
    }
#pragma unroll
    for (int nf = 0; nf < 4; ++nf)
      b_h[nf] = *reinterpret_cast<const s16x8*>(&cBh[(ntb+nf)*512 + loff]);
#pragma unroll
    for (int mf = 0; mf < 4; ++mf)
#pragma unroll
      for (int nf = 0; nf < 4; ++nf) {
        acc[mf][nf] = MFMA(a_h[mf], b_h[nf], acc[mf][nf]);
        acc[mf][nf] = MFMA(a_l[mf], b_h[nf], acc[mf][nf]);
      }
    __syncthreads();

    // ---- phase B: MFMA ah x bl; stage A[kt+1]; prefetch A[kt+2] ----
    s16x8 b_l[4];
#pragma unroll
    for (int nf = 0; nf < 4; ++nf)
      b_l[nf] = *reinterpret_cast<const s16x8*>(&blb[(ntb+nf)*512 + loff]);
#pragma unroll
    for (int mf = 0; mf < 4; ++mf)
#pragma unroll
      for (int nf = 0; nf < 4; ++nf)
        acc[mf][nf] = MFMA(a_h[mf], b_l[nf], acc[mf][nf]);
    if (kt < 127) {
      uint4 h4, l4; pack8(ra0, ra1, h4, l4);
      *reinterpret_cast<uint4*>(&nAh[awr]) = h4;
      *reinterpret_cast<uint4*>(&nAl[awr]) = l4;
      if (kt < 126) {
        ra0 = *reinterpret_cast<const float4*>(aptr + (kt+2)*32);
        ra1 = *reinterpret_cast<const float4*>(aptr + (kt+2)*32 + 4);
      }
    }
    __syncthreads();
  }

  // ---- epilogue ----
  const int lr = lane & 15, lg = lane >> 4;
  const int row0 = mb*128 + (wid >> 2) * 64;
  const int nloc = nb*256 + (wid & 3) * 64;
#pragma unroll
  for (int mf = 0; mf < 4; ++mf)
#pragma unroll
    for (int nf = 0; nf < 4; ++nf)
#pragma unroll
      for (int r = 0; r < 4; ++r)
        C[(size_t)(row0 + mf*16 + lg*4 + r) * ldc + nloc + nf*16 + lr] = acc[mf][nf][r];
}

// ===========================================================================
// Fallback GEMM (round-1, proven) used only if ws < 112MB.
// ===========================================================================
__device__ __forceinline__ void gemm_core_128x256(
    const float* __restrict__ A, const float* __restrict__ W,
    float* __restrict__ C, int ldw, int m0, int n0)
{
  __shared__ u16 Ah[128][40];
  __shared__ u16 Al[128][40];
  __shared__ u16 Bh[256][40];
  __shared__ u16 Bl[256][40];

  const int tid  = threadIdx.x;
  const int lane = tid & 63;
  const int wid  = tid >> 6;
  const int wm   = (wid >> 2) * 64;
  const int wn   = (wid & 3) * 64;
  const int lr   = lane & 15;
  const int lg   = lane >> 4;

  f32x4 acc[4][4];
#pragma unroll
  for (int i = 0; i < 4; ++i)
#pragma unroll
    for (int j = 0; j < 4; ++j) acc[i][j] = (f32x4){0.f, 0.f, 0.f, 0.f};

  const int ar  = tid >> 3;
  const int ak  = (tid & 7) * 4;
  const int bn  = tid & 255;
  const int bk0 = (tid >> 8) * 16;

  for (int kt = 0; kt < D_ / 32; ++kt) {
    const int k0 = kt * 32;
    __syncthreads();
#pragma unroll
    for (int j = 0; j < 2; ++j) {
      int r = ar + 64 * j;
      float4 v = *reinterpret_cast<const float4*>(&A[(size_t)(m0 + r) * D_ + k0 + ak]);
      u16 h0,h1,h2,h3,l0,l1,l2,l3;
      split2(v.x,h0,l0); split2(v.y,h1,l1); split2(v.z,h2,l2); split2(v.w,h3,l3);
      *reinterpret_cast<s16x4*>(&Ah[r][ak]) = (s16x4){(short)h0,(short)h1,(short)h2,(short)h3};
      *reinterpret_cast<s16x4*>(&Al[r][ak]) = (s16x4){(short)l0,(short)l1,(short)l2,(short)l3};
    }
    {
      const float* wp = W + (size_t)(k0 + bk0) * ldw + (n0 + bn);
#pragma unroll
      for (int q = 0; q < 4; ++q) {
        float v0 = wp[(q*4 + 0) * (size_t)ldw];
        float v1 = wp[(q*4 + 1) * (size_t)ldw];
        float v2 = wp[(q*4 + 2) * (size_t)ldw];
        float v3 = wp[(q*4 + 3) * (size_t)ldw];
        u16 h0,h1,h2,h3,l0,l1,l2,l3;
        split2(v0,h0,l0); split2(v1,h1,l1); split2(v2,h2,l2); split2(v3,h3,l3);
        *reinterpret_cast<s16x4*>(&Bh[bn][bk0 + q*4]) = (s16x4){(short)h0,(short)h1,(short)h2,(short)h3};
        *reinterpret_cast<s16x4*>(&Bl[bn][bk0 + q*4]) = (s16x4){(short)l0,(short)l1,(short)l2,(short)l3};
      }
    }
    __syncthreads();
    s16x8 a_h[4], a_l[4], b_h[4], b_l[4];
#pragma unroll
    for (int mf = 0; mf < 4; ++mf) {
      a_h[mf] = *reinterpret_cast<const s16x8*>(&Ah[wm + mf*16 + lr][lg*8]);
      a_l[mf] = *reinterpret_cast<const s16x8*>(&Al[wm + mf*16 + lr][lg*8]);
    }
#pragma unroll
    for (int nf = 0; nf < 4; ++nf) {
      b_h[nf] = *reinterpret_cast<const s16x8*>(&Bh[wn + nf*16 + lr][lg*8]);
      b_l[nf] = *reinterpret_cast<const s16x8*>(&Bl[wn + nf*16 + lr][lg*8]);
    }
#pragma unroll
    for (int mf = 0; mf < 4; ++mf)
#pragma unroll
      for (int nf = 0; nf < 4; ++nf) {
        acc[mf][nf] = MFMA(a_h[mf], b_h[nf], acc[mf][nf]);
        acc[mf][nf] = MFMA(a_l[mf], b_h[nf], acc[mf][nf]);
        acc[mf][nf] = MFMA(a_h[mf], b_l[nf], acc[mf][nf]);
      }
  }
#pragma unroll
  for (int mf = 0; mf < 4; ++mf)
#pragma unroll
    for (int nf = 0; nf < 4; ++nf)
#pragma unroll
      for (int r = 0; r < 4; ++r) {
        int row = m0 + wm + mf*16 + lg*4 + r;
        int col = n0 + wn + nf*16 + lr;
        C[(size_t)row * ldw + col] = acc[mf][nf][r];
      }
}

__global__ __launch_bounds__(512) void gemm_qkv_kernel(
    const float* __restrict__ X,
    const float* __restrict__ Wq, const float* __restrict__ Wk,
    const float* __restrict__ Wv,
    float* __restrict__ qb, float* __restrict__ kb, float* __restrict__ vb)
{
  int nbv = blockIdx.x;
  int m0 = blockIdx.y * 128;
  const float* W; float* C; int ldw, n0;
  if (nbv < 16)      { W = Wq; C = qb; ldw = HQ_*HD_;  n0 = nbv * 256; }
  else if (nbv < 20) { W = Wk; C = kb; ldw = HKV_*HD_; n0 = (nbv-16) * 256; }
  else               { W = Wv; C = vb; ldw = HKV_*HD_; n0 = (nbv-20) * 256; }
  gemm_core_128x256(X, W, C, ldw, m0, n0);
}

__global__ __launch_bounds__(512) void gemm_out_kernel(
    const float* __restrict__ A, const float* __restrict__ Wo, float* __restrict__ out)
{
  gemm_core_128x256(A, Wo, out, D_, blockIdx.y * 128, blockIdx.x * 256);
}

// ---------------------------------------------------------------------------
// RoPE in-place on q (b,s,32,128) and k (b,s,8,128), fp32.
// ---------------------------------------------------------------------------
__global__ __launch_bounds__(256) void rope_kernel(
    float* __restrict__ qb, float* __restrict__ kb,
    const float* __restrict__ cosT, const float* __restrict__ sinT)
{
  int idx = blockIdx.x * 256 + threadIdx.x;
  const int nq = B_ * S_ * HQ_ * (HD_/2);
  const int nk = B_ * S_ * HKV_ * (HD_/2);
  if (idx < nq) {
    int j = idx & 63;
    int h = (idx >> 6) & (HQ_ - 1);
    int bs = idx >> 11;
    float* p = qb + ((size_t)bs * HQ_ + h) * HD_;
    const float* cp = cosT + (size_t)bs * HD_;
    const float* sp = sinT + (size_t)bs * HD_;
    float x1 = p[j], x2 = p[j + 64];
    p[j]      = x1 * cp[j]      - x2 * sp[j];
    p[j + 64] = x2 * cp[j + 64] + x1 * sp[j + 64];
  } else if (idx < nq + nk) {
    int t2 = idx - nq;
    int j = t2 & 63;
    int h = (t2 >> 6) & (HKV_ - 1);
    int bs = t2 >> 9;
    float* p = kb + ((size_t)bs * HKV_ + h) * HD_;
    const float* cp = cosT + (size_t)bs * HD_;
    const float* sp = sinT + (size_t)bs * HD_;
    float x1 = p[j], x2 = p[j + 64];
    p[j]      = x1 * cp[j]      - x2 * sp[j];
    p[j + 64] = x2 * cp[j + 64] + x1 * sp[j + 64];
  }
}

// ---------------------------------------------------------------------------
// Flash attention (round-1 verified): grid (8 qtiles, 64 b*h), 512 thr.
// ---------------------------------------------------------------------------
__global__ __launch_bounds__(512) void attn_kernel(
    const float* __restrict__ qb, const float* __restrict__ kb,
    const float* __restrict__ vb, float* __restrict__ ob)
{
  __shared__ u16 Kh[64][136], Kl[64][136];
  __shared__ u16 Vh[128][72], Vl[128][72];
  __shared__ u16 Ph[8][16][72], Pl[8][16][72];

  const int tid  = threadIdx.x;
  const int lane = tid & 63;
  const int wid  = tid >> 6;
  const int lr   = lane & 15;
  const int lg   = lane >> 4;
  const int qt   = blockIdx.x;
  const int bh   = blockIdx.y;
  const int b    = bh >> 5, h = bh & 31, kvh = h >> 2;

  s16x8 qh[4], ql[4];
  {
    const int qrow = qt * 128 + wid * 16 + lr;
    const float* qp = qb + ((size_t)((b * S_ + qrow) * HQ_ + h)) * HD_;
#pragma unroll
    for (int kc = 0; kc < 4; ++kc) {
      const float* qp2 = qp + kc * 32 + lg * 8;
      float4 v0 = *reinterpret_cast<const float4*>(qp2);
      float4 v1 = *reinterpret_cast<const float4*>(qp2 + 4);
      u16 hh[8], ll[8];
      split2(v0.x,hh[0],ll[0]); split2(v0.y,hh[1],ll[1]);
      split2(v0.z,hh[2],ll[2]); split2(v0.w,hh[3],ll[3]);
      split2(v1.x,hh[4],ll[4]); split2(v1.y,hh[5],ll[5]);
      split2(v1.z,hh[6],ll[6]); split2(v1.w,hh[7],ll[7]);
      qh[kc] = (s16x8){(short)hh[0],(short)hh[1],(short)hh[2],(short)hh[3],
                       (short)hh[4],(short)hh[5],(short)hh[6],(short)hh[7]};
      ql[kc] = (s16x8){(short)ll[0],(short)ll[1],(short)ll[2],(short)ll[3],
                       (short)ll[4],(short)ll[5],(short)ll[6],(short)ll[7]};
    }
  }

  f32x4 acc_o[8];
#pragma unroll
  for (int df = 0; df < 8; ++df) acc_o[df] = (f32x4){0.f, 0.f, 0.f, 0.f};
  float m_run[4] = {-1e30f, -1e30f, -1e30f, -1e30f};
  float l_run[4] = {0.f, 0.f, 0.f, 0.f};

  const float* kbase = kb + ((size_t)(b * S_) * HKV_ + kvh) * HD_;
  const float* vbase = vb + ((size_t)(b * S_) * HKV_ + kvh) * HD_;

  for (int t = 0; t < S_ / 64; ++t) {
    const int kk0 = t * 64;
    __syncthreads();
#pragma unroll
    for (int j = 0; j < 4; ++j) {
      int idx = tid + 512 * j;
      int kk = idx >> 5, dq = (idx & 31) * 4;
      float4 v = *reinterpret_cast<const float4*>(kbase + (size_t)(kk0 + kk) * (HKV_*HD_) + dq);
      u16 h0,h1,h2,h3,l0,l1,l2,l3;
      split2(v.x,h0,l0); split2(v.y,h1,l1); split2(v.z,h2,l2); split2(v.w,h3,l3);
      *reinterpret_cast<s16x4*>(&Kh[kk][dq]) = (s16x4){(short)h0,(short)h1,(short)h2,(short)h3};
      *reinterpret_cast<s16x4*>(&Kl[kk][dq]) = (s16x4){(short)l0,(short)l1,(short)l2,(short)l3};
    }
    {
      int d = tid & 127;
      int kkb = (tid >> 7) * 16;
      const float* vcol = vbase + d;
#pragma unroll
      for (int jq = 0; jq < 4; ++jq) {
        u16 h4[4], l4[4];
#pragma unroll
        for (int e = 0; e < 4; ++e) {
          float val = vcol[(size_t)(kk0 + kkb + jq*4 + e) * (HKV_*HD_)];
          split2(val, h4[e], l4[e]);
        }
        *reinterpret_cast<s16x4*>(&Vh[d][kkb + jq*4]) = (s16x4){(short)h4[0],(short)h4[1],(short)h4[2],(short)h4[3]};
        *reinterpret_cast<s16x4*>(&Vl[d][kkb + jq*4]) = (s16x4){(short)l4[0],(short)l4[1],(short)l4[2],(short)l4[3]};
      }
    }
    __syncthreads();
    f32x4 accs[4];
#pragma unroll
    for (int nf = 0; nf < 4; ++nf) accs[nf] = (f32x4){0.f, 0.f, 0.f, 0.f};
#pragma unroll
    for (int nf = 0; nf < 4; ++nf) {
      int krow = nf * 16 + lr;
#pragma unroll
      for (int kc = 0; kc < 4; ++kc) {
        s16x8 kh8 = *reinterpret_cast<const s16x8*>(&Kh[krow][kc*32 + lg*8]);
        s16x8 kl8 = *reinterpret_cast<const s16x8*>(&Kl[krow][kc*32 + lg*8]);
        accs[nf] = MFMA(qh[kc], kh8, accs[nf]);
        accs[nf] = MFMA(ql[kc], kh8, accs[nf]);
        accs[nf] = MFMA(qh[kc], kl8, accs[nf]);
      }
    }
#pragma unroll
    for (int nf = 0; nf < 4; ++nf) accs[nf] *= SCALE_;
    float corr[4], rsum[4];
#pragma unroll
    for (int r = 0; r < 4; ++r) {
      float t0 = fmaxf(fmaxf(accs[0][r], accs[1][r]), fmaxf(accs[2][r], accs[3][r]));
      t0 = fmaxf(t0, __shfl_xor(t0, 1));
      t0 = fmaxf(t0, __shfl_xor(t0, 2));
      t0 = fmaxf(t0, __shfl_xor(t0, 4));
      t0 = fmaxf(t0, __shfl_xor(t0, 8));
      float mnew = fmaxf(m_run[r], t0);
      corr[r] = __expf(m_run[r] - mnew);
      m_run[r] = mnew;
      rsum[r] = 0.f;
    }
#pragma unroll
    for (int nf = 0; nf < 4; ++nf)
#pragma unroll
      for (int r = 0; r < 4; ++r) {
        float p = __expf(accs[nf][r] - m_run[r]);
        rsum[r] += p;
        u16 ph, pl;
        split2(p, ph, pl);
        Ph[wid][lg*4 + r][nf*16 + lr] = ph;
        Pl[wid][lg*4 + r][nf*16 + lr] = pl;
      }
#pragma unroll
    for (int r = 0; r < 4; ++r) {
      float s = rsum[r];
      s += __shfl_xor(s, 1); s += __shfl_xor(s, 2);
      s += __shfl_xor(s, 4); s += __shfl_xor(s, 8);
      l_run[r] = l_run[r] * corr[r] + s;
    }
#pragma unroll
    for (int df = 0; df < 8; ++df)
#pragma unroll
      for (int r = 0; r < 4; ++r) acc_o[df][r] *= corr[r];
    s16x8 pa_h[2], pa_l[2];
#pragma unroll
    for (int kc = 0; kc < 2; ++kc) {
      pa_h[kc] = *reinterpret_cast<const s16x8*>(&Ph[wid][lr][kc*32 + lg*8]);
      pa_l[kc] = *reinterpret_cast<const s16x8*>(&Pl[wid][lr][kc*32 + lg*8]);
    }
#pragma unroll
    for (int df = 0; df < 8; ++df) {
      int dcol = df * 16 + lr;
#pragma unroll
      for (int kc = 0; kc < 2; ++kc) {
        s16x8 vh8 = *reinterpret_cast<const s16x8*>(&Vh[dcol][kc*32 + lg*8]);
        s16x8 vl8 = *reinterpret_cast<const s16x8*>(&Vl[dcol][kc*32 + lg*8]);
        acc_o[df] = MFMA(pa_h[kc], vh8, acc_o[df]);
        acc_o[df] = MFMA(pa_l[kc], vh8, acc_o[df]);
        acc_o[df] = MFMA(pa_h[kc], vl8, acc_o[df]);
      }
    }
  }
  float inv_l[4];
#pragma unroll
  for (int r = 0; r < 4; ++r) inv_l[r] = 1.f / l_run[r];
#pragma unroll
  for (int df = 0; df < 8; ++df)
#pragma unroll
    for (int r = 0; r < 4; ++r) {
      int row = qt * 128 + wid * 16 + lg * 4 + r;
      ob[((size_t)((b * S_ + row) * HQ_ + h)) * HD_ + df*16 + lr] = acc_o[df][r] * inv_l[r];
    }
}

// ---------------------------------------------------------------------------
extern "C" void kernel_launch(void* const* d_in, const int* in_sizes, int n_in,
                              void* d_out, int out_size, void* d_ws, size_t ws_size,
                              hipStream_t stream)
{
  const float* hs   = (const float*)d_in[0];
  const float* cosT = (const float*)d_in[1];
  const float* sinT = (const float*)d_in[2];
  const float* Wq   = (const float*)d_in[3];
  const float* Wk   = (const float*)d_in[4];
  const float* Wv   = (const float*)d_in[5];
  const float* Wo   = (const float*)d_in[6];
  float* out = (float*)d_out;

  float* qb = (float*)d_ws;                 // 8388608 f32
  float* kb = qb + 8388608;                 // 2097152
  float* vb = kb + 2097152;                 // 2097152
  float* ab = vb + 2097152;                 // 8388608
  u16*   WF = (u16*)(ab + 8388608);

  const size_t WS144 = 83886080ULL + 67108864ULL;  // 150,994,944
  const size_t WS112 = 83886080ULL + 33554432ULL;  // 117,440,512
  int total = B_*S_*HQ_*(HD_/2) + B_*S_*HKV_*(HD_/2);

  if (ws_size >= WS144) {
    // WF(64MB): Wq-chunk hi@0 lo@8388608 | Wk hi@16777216 lo@20971520
    //           | Wv hi@25165824 lo@29360128
    frag_b<<<dim3(128,32), 256, 0, stream>>>(Wq, WF,          WF+8388608,  4096, 0,    128);
    frag_b<<<dim3(128,16), 256, 0, stream>>>(Wk, WF+16777216, WF+20971520, 1024, 0,    64);
    frag_b<<<dim3(128,16), 256, 0, stream>>>(Wv, WF+25165824, WF+29360128, 1024, 0,    64);
    gemm_p1<<<256, 512, 0, stream>>>(hs, ab, WF, qb, kb, vb, out, 0, 0);       // QA + K + V
    frag_b<<<dim3(128,32), 256, 0, stream>>>(Wq, WF,          WF+8388608,  4096, 2048, 128);
    gemm_p1<<<128, 512, 0, stream>>>(hs, ab, WF, qb, kb, vb, out, 1, 2048);    // QB
    rope_kernel<<<dim3((total + 255)/256), 256, 0, stream>>>(qb, kb, cosT, sinT);
    attn_kernel<<<dim3(8, 64), 512, 0, stream>>>(qb, kb, vb, ab);
    frag_b<<<dim3(128,64), 256, 0, stream>>>(Wo, WF,          WF+16777216, 4096, 0,    256);
    gemm_p1<<<256, 512, 0, stream>>>(hs, ab, WF, qb, kb, vb, out, 3, 0);       // OUT
  } else if (ws_size >= WS112) {
    frag_b<<<dim3(128,32), 256, 0, stream>>>(Wq, WF, WF+8388608, 4096, 0, 128);
    gemm_p1<<<128, 512, 0, stream>>>(hs, ab, WF, qb, kb, vb, out, 1, 0);       // QA
    frag_b<<<dim3(128,32), 256, 0, stream>>>(Wq, WF, WF+8388608, 4096, 2048, 128);
    gemm_p1<<<128, 512, 0, stream>>>(hs, ab, WF, qb, kb, vb, out, 1, 2048);    // QB
    frag_b<<<dim3(128,16), 256, 0, stream>>>(Wk, WF,           WF+4194304,  1024, 0, 64);
    frag_b<<<dim3(128,16), 256, 0, stream>>>(Wv, WF+8388608,   WF+12582912, 1024, 0, 64);
    gemm_p1<<<128, 512, 0, stream>>>(hs, ab, WF, qb, kb, vb, out, 2, 0);       // K + V
    rope_kernel<<<dim3((total + 255)/256), 256, 0, stream>>>(qb, kb, cosT, sinT);
    attn_kernel<<<dim3(8, 64), 512, 0, stream>>>(qb, kb, vb, ab);
    frag_b<<<dim3(128,32), 256, 0, stream>>>(Wo, WF, WF+8388608, 4096, 0, 128);
    gemm_p1<<<128, 512, 0, stream>>>(hs, ab, WF, qb, kb, vb, out, 4, 0);       // OUT-A
    frag_b<<<dim3(128,32), 256, 0, stream>>>(Wo, WF, WF+8388608, 4096, 2048, 128);
    gemm_p1<<<128, 512, 0, stream>>>(hs, ab, WF, qb, kb, vb, out, 4, 2048);    // OUT-B
  } else {
    // fallback: round-1 path (84 MB ws)
    gemm_qkv_kernel<<<dim3(24, 16), 512, 0, stream>>>(hs, Wq, Wk, Wv, qb, kb, vb);
    rope_kernel<<<dim3((total + 255)/256), 256, 0, stream>>>(qb, kb, cosT, sinT);
    attn_kernel<<<dim3(8, 64), 512, 0, stream>>>(qb, kb, vb, ab);
    gemm_out_kernel<<<dim3(16, 16), 512, 0, stream>>>(ab, Wo, out);
  }
}